// Round 1
// baseline (102.726 us; speedup 1.0000x reference)
//
#include <hip/hip_runtime.h>
#include <math.h>

// Problem constants
#define DMODEL 256
#define NSEQ   512
#define MSEQ   512
#define NHEAD  4
#define DHEAD  64

// ws layout (float offsets)
#define WS_Q      0            // [512][256]
#define WS_K      131072       // [512][256]
#define WS_V      262144       // [512][256]
#define WS_WPE    393216       // [512][256][4]  (n, d, h)
#define WS_SCORES 917504       // [4][512][512]
// total floats = 1966080 -> 7.5 MB

// ---------------------------------------------------------------------------
// Kernel A: q/k/v projections.  Y = X @ W^T + b   (fp32)
// grid = 3 * 64 blocks (matrix, 8-row block), 256 threads (thread = out col)
// x-row loads are block-uniform -> scalar loads; W row streamed per thread.
// ---------------------------------------------------------------------------
__global__ __launch_bounds__(256) void proj_qkv(
    const float* __restrict__ xq, const float* __restrict__ xk,
    const float* __restrict__ xv,
    const float* __restrict__ Wq, const float* __restrict__ bq,
    const float* __restrict__ Wk, const float* __restrict__ bk,
    const float* __restrict__ Wv, const float* __restrict__ bv,
    float* __restrict__ ws)
{
    int bid = blockIdx.x;
    int mat = bid >> 6;       // 0=q 1=k 2=v
    int rb  = bid & 63;       // 8-row block
    const float* X; const float* W; const float* b; float* Y;
    if (mat == 0)      { X = xq; W = Wq; b = bq; Y = ws + WS_Q; }
    else if (mat == 1) { X = xk; W = Wk; b = bk; Y = ws + WS_K; }
    else               { X = xv; W = Wv; b = bv; Y = ws + WS_V; }

    int c  = threadIdx.x;
    int r0 = rb * 8;
    float acc[8];
    float bias = b[c];
#pragma unroll
    for (int r = 0; r < 8; ++r) acc[r] = bias;

    const float4* Wrow = (const float4*)(W + (size_t)c * DMODEL);
    for (int d4 = 0; d4 < 64; ++d4) {
        float4 w = Wrow[d4];
#pragma unroll
        for (int r = 0; r < 8; ++r) {
            float4 x = ((const float4*)(X + (size_t)(r0 + r) * DMODEL))[d4];
            acc[r] += w.x * x.x + w.y * x.y + w.z * x.z + w.w * x.w;
        }
    }
#pragma unroll
    for (int r = 0; r < 8; ++r)
        Y[(size_t)(r0 + r) * DMODEL + c] = acc[r];
}

// ---------------------------------------------------------------------------
// Kernel B: W'[n][d][h] = sum_dh q[n][h*64+dh] * Wp[h*64+dh][d]
// grid = 256 blocks (2 n each), 256 threads (thread = d).
// Wp column reads are perfectly coalesced; q reads are uniform (scalarized).
// ---------------------------------------------------------------------------
__global__ __launch_bounds__(256) void make_wpeff(
    const float* __restrict__ Wp, float* __restrict__ ws)
{
    const float* q   = ws + WS_Q;
    float*       wpe = ws + WS_WPE;
    int n0 = blockIdx.x * 2;
    int d  = threadIdx.x;

    const float* q0 = q + (size_t)n0 * DMODEL;
    const float* q1 = q0 + DMODEL;

    float acc0[4] = {0.f, 0.f, 0.f, 0.f};
    float acc1[4] = {0.f, 0.f, 0.f, 0.f};
#pragma unroll
    for (int h = 0; h < 4; ++h) {
        for (int dh = 0; dh < 64; ++dh) {
            int c = h * 64 + dh;
            float w = Wp[(size_t)c * DMODEL + d];
            acc0[h] += q0[c] * w;
            acc1[h] += q1[c] * w;
        }
    }
    *(float4*)&wpe[(size_t)n0 * 1024 + d * 4] =
        make_float4(acc0[0], acc0[1], acc0[2], acc0[3]);
    *(float4*)&wpe[(size_t)(n0 + 1) * 1024 + d * 4] =
        make_float4(acc1[0], acc1[1], acc1[2], acc1[3]);
}

// ---------------------------------------------------------------------------
// Kernel D: the HBM-streaming kernel.
// scores_p[h][n][m] = sum_d input_p[n,m,d] * W'[n][d][h]
// grid = 1024 blocks (n, m-half), 256 threads (thread = one m row).
// W'[n] (4 KB) staged in LDS; all compute-loop LDS reads are broadcast.
// ---------------------------------------------------------------------------
__global__ __launch_bounds__(256) void p_scores(
    const float* __restrict__ Xp, float* __restrict__ ws)
{
    const float* wpe    = ws + WS_WPE;
    float*       scores = ws + WS_SCORES;

    int bid  = blockIdx.x;
    int n    = bid >> 1;
    int half = bid & 1;
    int m    = half * 256 + threadIdx.x;

    __shared__ float4 wl[256];  // [d] -> (h0,h1,h2,h3)
    wl[threadIdx.x] = ((const float4*)(wpe + (size_t)n * 1024))[threadIdx.x];
    __syncthreads();

    const float4* xrow =
        (const float4*)(Xp + (size_t)((size_t)n * MSEQ + m) * DMODEL);
    float4 acc = make_float4(0.f, 0.f, 0.f, 0.f);
#pragma unroll 8
    for (int d4 = 0; d4 < 64; ++d4) {
        float4 x  = xrow[d4];
        float4 w0 = wl[d4 * 4 + 0];
        float4 w1 = wl[d4 * 4 + 1];
        float4 w2 = wl[d4 * 4 + 2];
        float4 w3 = wl[d4 * 4 + 3];
        acc.x += x.x * w0.x + x.y * w1.x + x.z * w2.x + x.w * w3.x;
        acc.y += x.x * w0.y + x.y * w1.y + x.z * w2.y + x.w * w3.y;
        acc.z += x.x * w0.z + x.y * w1.z + x.z * w2.z + x.w * w3.z;
        acc.w += x.x * w0.w + x.y * w1.w + x.z * w2.w + x.w * w3.w;
    }
    size_t base = (size_t)n * MSEQ + m;
    scores[0 * 262144 + base] = acc.x;
    scores[1 * 262144 + base] = acc.y;
    scores[2 * 262144 + base] = acc.z;
    scores[3 * 262144 + base] = acc.w;
}

// ---------------------------------------------------------------------------
// Kernel C: scores = 0.125 * (scores_p + q.k + q.bp)
// grid = 4h * 8 * 8 = 256 blocks (64x64 output tile), 256 threads.
// LDS tiles padded to 76 floats/row -> <=2-way bank aliasing on b128 reads.
// ---------------------------------------------------------------------------
__global__ __launch_bounds__(256) void qk_scores(
    const float* __restrict__ bp, float* __restrict__ ws)
{
    const float* q      = ws + WS_Q;
    const float* k      = ws + WS_K;
    float*       scores = ws + WS_SCORES;

    int bid = blockIdx.x;
    int h   = bid >> 6;
    int nt  = (bid >> 3) & 7;
    int mt  = bid & 7;
    int n0  = nt * 64, m0 = mt * 64;

    __shared__ float qs[64][76];
    __shared__ float ks[64][76];
    __shared__ float qb[64];

    int tid = threadIdx.x;
#pragma unroll
    for (int rep = 0; rep < 4; ++rep) {
        int idx = rep * 1024 + tid * 4;
        int row = idx >> 6, col = idx & 63;
        *(float4*)&qs[row][col] =
            *(const float4*)&q[(size_t)(n0 + row) * DMODEL + h * 64 + col];
        *(float4*)&ks[row][col] =
            *(const float4*)&k[(size_t)(m0 + row) * DMODEL + h * 64 + col];
    }
    __syncthreads();

    if (tid < 64) {
        float s = 0.f;
        for (int dh = 0; dh < 64; ++dh) s += qs[tid][dh] * bp[h * 64 + dh];
        qb[tid] = s;
    }
    __syncthreads();

    int tn = tid >> 4, tm = tid & 15;
    float acc[4][4] = {};
    for (int kk = 0; kk < 64; kk += 4) {
        float4 qf[4], kf[4];
#pragma unroll
        for (int i = 0; i < 4; ++i) {
            qf[i] = *(const float4*)&qs[tn * 4 + i][kk];
            kf[i] = *(const float4*)&ks[tm * 4 + i][kk];
        }
#pragma unroll
        for (int i = 0; i < 4; ++i)
#pragma unroll
            for (int j = 0; j < 4; ++j)
                acc[i][j] += qf[i].x * kf[j].x + qf[i].y * kf[j].y +
                             qf[i].z * kf[j].z + qf[i].w * kf[j].w;
    }

#pragma unroll
    for (int i = 0; i < 4; ++i) {
        int n = n0 + tn * 4 + i;
        float qbn = qb[tn * 4 + i];
        float4* p = (float4*)&scores[(size_t)h * 262144 +
                                     (size_t)n * MSEQ + m0 + tm * 4];
        float4 sp = *p;
        sp.x = 0.125f * (sp.x + acc[i][0] + qbn);
        sp.y = 0.125f * (sp.y + acc[i][1] + qbn);
        sp.z = 0.125f * (sp.z + acc[i][2] + qbn);
        sp.w = 0.125f * (sp.w + acc[i][3] + qbn);
        *p = sp;
    }
}

// ---------------------------------------------------------------------------
// Kernel E: masked softmax over m + attn @ v, writes final output.
// grid = 4h * 64 groups (8 n each) = 256 blocks, 256 threads.
// v[h] is read once per block (32 MB total L2 traffic).
// ---------------------------------------------------------------------------
__global__ __launch_bounds__(256) void softmax_av(
    const unsigned char* __restrict__ mask,
    float* __restrict__ out, float* __restrict__ ws)
{
    const float* v      = ws + WS_V;
    const float* scores = ws + WS_SCORES;

    int bid = blockIdx.x;
    int h   = bid >> 6;
    int g   = bid & 63;
    int n0  = g * 8;

    __shared__ float  pl[MSEQ * 8];   // [m][j]  16 KB
    __shared__ float4 red4[256];      // reduce scratch 4 KB
    __shared__ float  wred[4];

    int tid  = threadIdx.x;
    int lane = tid & 63, wv = tid >> 6;

    for (int j = 0; j < 8; ++j) {
        int n = n0 + j;
        const float* srow = scores + (size_t)h * 262144 + (size_t)n * MSEQ;
        float s0 = srow[tid];
        float s1 = srow[tid + 256];
        if (mask[tid])       s0 = -INFINITY;
        if (mask[tid + 256]) s1 = -INFINITY;

        float mx = fmaxf(s0, s1);
#pragma unroll
        for (int off = 32; off; off >>= 1) mx = fmaxf(mx, __shfl_xor(mx, off));
        if (lane == 0) wred[wv] = mx;
        __syncthreads();
        mx = fmaxf(fmaxf(wred[0], wred[1]), fmaxf(wred[2], wred[3]));

        float e0 = __expf(s0 - mx);
        float e1 = __expf(s1 - mx);
        float sm = e0 + e1;
#pragma unroll
        for (int off = 32; off; off >>= 1) sm += __shfl_xor(sm, off);
        __syncthreads();                 // wred consumed by all before rewrite
        if (lane == 0) wred[wv] = sm;
        __syncthreads();
        sm = wred[0] + wred[1] + wred[2] + wred[3];
        float rinv = 1.0f / sm;

        pl[(size_t)tid * 8 + j]         = e0 * rinv;
        pl[(size_t)(tid + 256) * 8 + j] = e1 * rinv;
        __syncthreads();
    }

    // AV: thread = (dhq 0..15, mq 0..15); each covers 32 m values.
    int dhq = tid & 15, mq = tid >> 4;
    float acc[8][4] = {};
    for (int i = 0; i < 32; ++i) {
        int m = mq * 32 + i;
        float4 vv = *(const float4*)&v[(size_t)m * DMODEL + h * 64 + dhq * 4];
        float4 pa = *(const float4*)&pl[m * 8];
        float4 pb = *(const float4*)&pl[m * 8 + 4];
#pragma unroll
        for (int j = 0; j < 4; ++j) {
            float p = (&pa.x)[j];
            acc[j][0] += p * vv.x; acc[j][1] += p * vv.y;
            acc[j][2] += p * vv.z; acc[j][3] += p * vv.w;
        }
#pragma unroll
        for (int j = 0; j < 4; ++j) {
            float p = (&pb.x)[j];
            acc[4 + j][0] += p * vv.x; acc[4 + j][1] += p * vv.y;
            acc[4 + j][2] += p * vv.z; acc[4 + j][3] += p * vv.w;
        }
    }

    // reduce the 16 mq partials per (n, dh) and store
    for (int j = 0; j < 8; ++j) {
        red4[mq * 16 + dhq] =
            make_float4(acc[j][0], acc[j][1], acc[j][2], acc[j][3]);
        __syncthreads();
        if (tid < 64) {
            int dq = tid >> 2, x = tid & 3;
            float s = 0.f;
#pragma unroll
            for (int qq = 0; qq < 16; ++qq)
                s += ((const float*)&red4[qq * 16 + dq])[x];
            out[(size_t)(n0 + j) * DMODEL + h * 64 + tid] = s;
        }
        __syncthreads();
    }
}

// ---------------------------------------------------------------------------
extern "C" void kernel_launch(void* const* d_in, const int* in_sizes, int n_in,
                              void* d_out, int out_size, void* d_ws,
                              size_t ws_size, hipStream_t stream)
{
    const float* xq = (const float*)d_in[0];
    const float* xk = (const float*)d_in[1];
    const float* xv = (const float*)d_in[2];
    const float* xp = (const float*)d_in[3];
    const unsigned char* mask = (const unsigned char*)d_in[4];
    const float* Wq = (const float*)d_in[5];
    const float* bq = (const float*)d_in[6];
    const float* Wk = (const float*)d_in[7];
    const float* bk = (const float*)d_in[8];
    const float* Wv = (const float*)d_in[9];
    const float* bv = (const float*)d_in[10];
    const float* Wp = (const float*)d_in[11];
    const float* bp = (const float*)d_in[12];
    float* out = (float*)d_out;
    float* ws  = (float*)d_ws;

    proj_qkv  <<<192,  256, 0, stream>>>(xq, xk, xv, Wq, bq, Wk, bk, Wv, bv, ws);
    make_wpeff<<<256,  256, 0, stream>>>(Wp, ws);
    p_scores  <<<1024, 256, 0, stream>>>(xp, ws);
    qk_scores <<<256,  256, 0, stream>>>(bp, ws);
    softmax_av<<<256,  256, 0, stream>>>(mask, out, ws);
}